// Round 5
// baseline (288.750 us; speedup 1.0000x reference)
//
#include <hip/hip_runtime.h>
#include <hip/hip_bf16.h>

// Problem constants (from reference)
#define NN 50000
#define NE 800000
#define HD 128

typedef unsigned short u16;
typedef __attribute__((ext_vector_type(8))) short short8;
typedef __attribute__((ext_vector_type(4))) float floatx4;
#define MFMA __builtin_amdgcn_mfma_f32_16x16x32_bf16

__device__ __forceinline__ float bf2f(u16 v) {
    union { unsigned int u; float f; } x; x.u = ((unsigned int)v) << 16; return x.f;
}
__device__ __forceinline__ u16 f2bf(float f) {
    union { unsigned int u; float f; } x; x.f = f;
    unsigned int r = x.u + 0x7fff + ((x.u >> 16) & 1);
    return (u16)(r >> 16);
}
// fast ELU: t>0 ? t : exp2(t*log2e)-1  (v_exp_f32 path, ~4 instrs)
__device__ __forceinline__ float elu_fast(float t) {
    return t > 0.f ? t : (__builtin_amdgcn_exp2f(t * 1.44269504088896f) - 1.f);
}

// convert 8 consecutive f32 to a bf16 A-fragment
__device__ __forceinline__ short8 cvt8(const float* p) {
    const float4* q = (const float4*)p;
    float4 a = q[0], b = q[1];
    short8 r;
    r[0] = (short)f2bf(a.x); r[1] = (short)f2bf(a.y); r[2] = (short)f2bf(a.z); r[3] = (short)f2bf(a.w);
    r[4] = (short)f2bf(b.x); r[5] = (short)f2bf(b.y); r[6] = (short)f2bf(b.z); r[7] = (short)f2bf(b.w);
    return r;
}

// K0: weight prep -> bf16 transposed layouts [c][k]
__global__ void k_wb(const float* __restrict__ we0, const float* __restrict__ we1,
                     const float* __restrict__ wn0, const float* __restrict__ wn1,
                     u16* __restrict__ wcombt, u16* __restrict__ we1t,
                     u16* __restrict__ wn0t, u16* __restrict__ wn1t) {
    int i = blockIdx.x * 256 + threadIdx.x;
    if (i < 32768) {                       // wcombt
        int c = i >> 7, k = i & 127;
        float v;
        if (c < 128) v = we0[k * 128 + c] + we0[(256 + k) * 128 + c];
        else { int cc = c - 128; v = we0[(128 + k) * 128 + cc] - we0[(256 + k) * 128 + cc]; }
        wcombt[i] = f2bf(v);
    } else if (i < 49152) {                // we1t
        int j = i - 32768; int c = j >> 7, k = j & 127;
        we1t[j] = f2bf(we1[k * 128 + c]);
    } else if (i < 81920) {                // wn0t (k = 0..255)
        int j = i - 49152; int c = j >> 8, k = j & 255;
        wn0t[j] = f2bf(wn0[k * 128 + c]);
    } else if (i < 98304) {                // wn1t
        int j = i - 81920; int c = j >> 7, k = j & 127;
        wn1t[j] = f2bf(wn1[k * 128 + c]);
    }
}

// K2: MFMA [P|Q] = x @ Wcomb. 64 rows/block, 4 waves, LDS-staged coalesced output.
// p2 layout INTERLEAVED quads: p2[n][4i+0,1] = P[2i],P[2i+1] ; p2[n][4i+2,3] = x[2i],x[2i+1] (bf16)
// qb[n][128] = Q (bf16)
__global__ __launch_bounds__(256) void k_pq_mfma(const float* __restrict__ x,
                                                 const u16* __restrict__ wcombt,
                                                 u16* __restrict__ p2, u16* __restrict__ qb) {
    __shared__ u16 pq[64 * 264];   // p2 tile, pad 8 u16
    __shared__ u16 qt[64 * 136];   // qb tile, pad 8 u16
    int r0 = blockIdx.x * 64;
    int tid = threadIdx.x, wid = tid >> 6, lane = tid & 63;
    int arow = lane & 15, kblk = lane >> 4;
    // x -> interleaved x-slots of pq tile
    for (int s = tid; s < 64 * 64; s += 256) {      // 64 rows x 64 pairs
        int r = s >> 6, i = s & 63;
        int n = r0 + r;
        float2 v = (n < NN) ? *(const float2*)&x[(size_t)n * 128 + 2 * i] : make_float2(0.f, 0.f);
        ushort2 o = { f2bf(v.x), f2bf(v.y) };
        *(ushort2*)&pq[r * 264 + 4 * i + 2] = o;
    }
    floatx4 acc[16];
#pragma unroll
    for (int n0 = 0; n0 < 16; n0++) acc[n0] = (floatx4)(0.f);
    int nrow = r0 + wid * 16 + arow; if (nrow >= NN) nrow = NN - 1;
#pragma unroll
    for (int ks = 0; ks < 4; ks++) {
        short8 a = cvt8(&x[(size_t)nrow * 128 + ks * 32 + kblk * 8]);
#pragma unroll
        for (int n0 = 0; n0 < 16; n0++) {
            short8 b = *(const short8*)&wcombt[(size_t)(n0 * 16 + arow) * 128 + ks * 32 + kblk * 8];
            acc[n0] = MFMA(a, b, acc[n0], 0, 0, 0);
        }
    }
    // epilogue into LDS (u16 scatter is cheap in LDS)
#pragma unroll
    for (int n0 = 0; n0 < 16; n0++) {
#pragma unroll
        for (int j = 0; j < 4; j++) {
            int r = wid * 16 + kblk * 4 + j;
            int col = n0 * 16 + arow;
            u16 v = f2bf(acc[n0][j]);
            if (col < 128) pq[r * 264 + 4 * (col >> 1) + (col & 1)] = v;
            else qt[r * 136 + (col - 128)] = v;
        }
    }
    __syncthreads();
    // coalesced flush: p2 (32 short8/row), qb (16 short8/row)
    for (int s = tid; s < 64 * 32; s += 256) {
        int r = s >> 5, cb = (s & 31) * 8;
        int n = r0 + r;
        if (n < NN) *(short8*)&p2[(size_t)n * 256 + cb] = *(const short8*)&pq[r * 264 + cb];
    }
    for (int s = tid; s < 64 * 16; s += 256) {
        int r = s >> 4, cb = (s & 15) * 8;
        int n = r0 + r;
        if (n < NN) *(short8*)&qb[(size_t)n * 128 + cb] = *(const short8*)&qt[r * 136 + cb];
    }
}

// K3: in-degree histogram, 4 edges/thread
__global__ void k_hist(const int* __restrict__ ei, int* __restrict__ cnt) {
    int e = (blockIdx.x * 256 + threadIdx.x) * 4;
    if (e + 4 <= NE) {
        int4 d = *(const int4*)&ei[NE + e];
        atomicAdd(&cnt[d.x], 1); atomicAdd(&cnt[d.y], 1);
        atomicAdd(&cnt[d.z], 1); atomicAdd(&cnt[d.w], 1);
    } else {
        for (int t = e; t < NE; t++) atomicAdd(&cnt[ei[NE + t]], 1);
    }
}

// K4a: per-block (512) inclusive scan
__global__ void k_scan1(const int* __restrict__ cnt, int* __restrict__ incl, int* __restrict__ bsum) {
    __shared__ int s[512];
    int i = blockIdx.x * 512 + threadIdx.x;
    int v = (i < NN) ? cnt[i] : 0;
    s[threadIdx.x] = v; __syncthreads();
    for (int off = 1; off < 512; off <<= 1) {
        int t = (threadIdx.x >= (unsigned)off) ? s[threadIdx.x - off] : 0;
        __syncthreads();
        s[threadIdx.x] += t; __syncthreads();
    }
    if (i < NN) incl[i] = s[threadIdx.x];
    if (threadIdx.x == 511) bsum[blockIdx.x] = s[511];
}

// K4b: exclusive scan of block sums (nb <= 128)
__global__ void k_scan2(int* __restrict__ bsum, int nb) {
    __shared__ int s[128];
    int t = threadIdx.x;
    s[t] = (t < nb) ? bsum[t] : 0;
    __syncthreads();
    if (t == 0) { int run = 0; for (int b = 0; b < nb; b++) { int v = s[b]; s[b] = run; run += v; } }
    __syncthreads();
    if (t < nb) bsum[t] = s[t];
}

// K4c
__global__ void k_scan3(const int* __restrict__ incl, const int* __restrict__ bsum,
                        const int* __restrict__ cnt, int* __restrict__ offs, int* __restrict__ cursor) {
    int i = blockIdx.x * 512 + threadIdx.x;
    if (i < NN) {
        int e = incl[i] + bsum[i >> 9];
        offs[i + 1] = e;
        cursor[i] = e - cnt[i];
        if (i == 0) offs[0] = 0;
    }
}

// K5: scatter edge srcs into CSR slots grouped by dst (4 edges/thread, int4)
__global__ void k_slots(const int* __restrict__ ei, int* __restrict__ cursor, int* __restrict__ srcs) {
    int e = (blockIdx.x * 256 + threadIdx.x) * 4;
    if (e + 4 <= NE) {
        int4 sv = *(const int4*)&ei[e];
        int4 dv = *(const int4*)&ei[NE + e];
        int p0 = atomicAdd(&cursor[dv.x], 1); srcs[p0] = sv.x;
        int p1 = atomicAdd(&cursor[dv.y], 1); srcs[p1] = sv.y;
        int p2_ = atomicAdd(&cursor[dv.z], 1); srcs[p2_] = sv.z;
        int p3 = atomicAdd(&cursor[dv.w], 1); srcs[p3] = sv.w;
    } else {
        for (int t = e; t < NE; t++) {
            int p = atomicAdd(&cursor[ei[NE + t]], 1);
            srcs[p] = ei[t];
        }
    }
}

// K6: one wave per node. Each lane owns channels 2l,2l+1 of BOTH esum and xsum
// via the interleaved p2 quads. Outputs:
//   esumx[n][0:128]   = esum/max(cnt,1)
//   esumx[n][128:256] = (xsum - cnt*x[n])/max(cnt,1)
__global__ __launch_bounds__(256) void k_agg(const u16* __restrict__ p2, const u16* __restrict__ qb,
                                             const int* __restrict__ offs, const int* __restrict__ srcs,
                                             u16* __restrict__ esumx) {
    int wave = threadIdx.x >> 6, lane = threadIdx.x & 63;
    int n = blockIdx.x * 4 + wave;
    if (n >= NN) return;
    int beg = offs[n], end = offs[n + 1];
    ushort2 qv = *(const ushort2*)(qb + (size_t)n * 128 + 2 * lane);
    float q0 = bf2f(qv.x), q1 = bf2f(qv.y);
    float e0 = 0.f, e1 = 0.f, s0 = 0.f, s1 = 0.f;
    int s = beg;
    for (; s + 8 <= end; s += 8) {
        int sr[8];
#pragma unroll
        for (int j = 0; j < 8; j++) sr[j] = srcs[s + j];
        ushort4 v[8];
#pragma unroll
        for (int j = 0; j < 8; j++) v[j] = *(const ushort4*)(p2 + (size_t)sr[j] * 256 + 4 * lane);
#pragma unroll
        for (int j = 0; j < 8; j++) {
            float t0 = bf2f(v[j].x) + q0, t1 = bf2f(v[j].y) + q1;
            e0 += elu_fast(t0); e1 += elu_fast(t1);
            s0 += bf2f(v[j].z); s1 += bf2f(v[j].w);
        }
    }
    for (; s < end; ++s) {
        ushort4 v = *(const ushort4*)(p2 + (size_t)srcs[s] * 256 + 4 * lane);
        float t0 = bf2f(v.x) + q0, t1 = bf2f(v.y) + q1;
        e0 += elu_fast(t0); e1 += elu_fast(t1);
        s0 += bf2f(v.z); s1 += bf2f(v.w);
    }
    float cntf = (float)(end - beg);
    float inv = 1.f / fmaxf(cntf, 1.f);
    ushort2 xo = *(const ushort2*)(p2 + (size_t)n * 256 + 4 * lane + 2);  // own x, ch 2l,2l+1
    s0 = (s0 - cntf * bf2f(xo.x)) * inv;
    s1 = (s1 - cntf * bf2f(xo.y)) * inv;
    e0 *= inv; e1 *= inv;
    ushort2 oe = { f2bf(e0), f2bf(e1) };
    ushort2 os = { f2bf(s0), f2bf(s1) };
    *(ushort2*)(esumx + (size_t)n * 256 + 2 * lane) = oe;
    *(ushort2*)(esumx + (size_t)n * 256 + 128 + 2 * lane) = os;
}

// K7: MFMA node MLP. 64 rows/block, 4 waves; each wave owns rows wid*16..wid*16+15
// (no inter-wave tile sharing -> no barriers between stages; within-wave DS ordering
// is guaranteed by hardware). Coalesced float4 epilogue.
__global__ __launch_bounds__(256) void k_node_mfma(const float* __restrict__ x,
                                                   const u16* __restrict__ esumx,
                                                   const u16* __restrict__ we1t,
                                                   const u16* __restrict__ wn0t,
                                                   const u16* __restrict__ wn1t,
                                                   float* __restrict__ out) {
    __shared__ u16 tile[64 * 136];   // pad 8 u16
    int r0 = blockIdx.x * 64;
    int tid = threadIdx.x, wid = tid >> 6, lane = tid & 63;
    int arow = lane & 15, kblk = lane >> 4;
    // stage xsum' (esumx hi half) into tile
    for (int s = tid; s < 64 * 16; s += 256) {
        int r = s >> 4, cb = (s & 15) * 8;
        int n = r0 + r; if (n >= NN) n = NN - 1;
        *(short8*)&tile[r * 136 + cb] = *(const short8*)&esumx[(size_t)n * 256 + 128 + cb];
    }
    __syncthreads();
    int rbase = wid * 16;
    int nrow = r0 + rbase + arow; if (nrow >= NN) nrow = NN - 1;
    floatx4 acc[8];
    // ---- stage 1: T = esum/cnt @ We1
#pragma unroll
    for (int n0 = 0; n0 < 8; n0++) acc[n0] = (floatx4)(0.f);
#pragma unroll
    for (int ks = 0; ks < 4; ks++) {
        short8 a = *(const short8*)&esumx[(size_t)nrow * 256 + ks * 32 + kblk * 8];
#pragma unroll
        for (int n0 = 0; n0 < 8; n0++) {
            short8 b = *(const short8*)&we1t[(size_t)(n0 * 16 + arow) * 128 + ks * 32 + kblk * 8];
            acc[n0] = MFMA(a, b, acc[n0], 0, 0, 0);
        }
    }
    // ---- m = T + xsum' (in place; own wave's rows only)
#pragma unroll
    for (int n0 = 0; n0 < 8; n0++)
#pragma unroll
        for (int j = 0; j < 4; j++) {
            int rloc = rbase + kblk * 4 + j;
            int col = n0 * 16 + arow;
            float m = acc[n0][j] + bf2f(tile[rloc * 136 + col]);
            tile[rloc * 136 + col] = f2bf(m);
        }
    // ---- stage 2: h = ELU(x@Wn0a + m@Wn0b)
#pragma unroll
    for (int n0 = 0; n0 < 8; n0++) acc[n0] = (floatx4)(0.f);
#pragma unroll
    for (int ks = 0; ks < 4; ks++) {
        short8 ax = cvt8(&x[(size_t)nrow * 128 + ks * 32 + kblk * 8]);
        short8 am = *(const short8*)&tile[(rbase + arow) * 136 + ks * 32 + kblk * 8];
#pragma unroll
        for (int n0 = 0; n0 < 8; n0++) {
            short8 bx = *(const short8*)&wn0t[(size_t)(n0 * 16 + arow) * 256 + ks * 32 + kblk * 8];
            short8 bm = *(const short8*)&wn0t[(size_t)(n0 * 16 + arow) * 256 + 128 + ks * 32 + kblk * 8];
            acc[n0] = MFMA(ax, bx, acc[n0], 0, 0, 0);
            acc[n0] = MFMA(am, bm, acc[n0], 0, 0, 0);
        }
    }
    // ---- h into tile (own rows; stage-2 reads of these rows are by this wave only)
#pragma unroll
    for (int n0 = 0; n0 < 8; n0++)
#pragma unroll
        for (int j = 0; j < 4; j++) {
            int rloc = rbase + kblk * 4 + j;
            int col = n0 * 16 + arow;
            tile[rloc * 136 + col] = f2bf(elu_fast(acc[n0][j]));
        }
    // ---- stage 3: r = h@Wn1
#pragma unroll
    for (int n0 = 0; n0 < 8; n0++) acc[n0] = (floatx4)(0.f);
#pragma unroll
    for (int ks = 0; ks < 4; ks++) {
        short8 a = *(const short8*)&tile[(rbase + arow) * 136 + ks * 32 + kblk * 8];
#pragma unroll
        for (int n0 = 0; n0 < 8; n0++) {
            short8 b = *(const short8*)&wn1t[(size_t)(n0 * 16 + arow) * 128 + ks * 32 + kblk * 8];
            acc[n0] = MFMA(a, b, acc[n0], 0, 0, 0);
        }
    }
    // ---- r into tile (bf16), then coalesced epilogue
#pragma unroll
    for (int n0 = 0; n0 < 8; n0++)
#pragma unroll
        for (int j = 0; j < 4; j++)
            tile[(rbase + kblk * 4 + j) * 136 + n0 * 16 + arow] = f2bf(acc[n0][j]);
    __syncthreads();
    for (int s = tid; s < 64 * 32; s += 256) {
        int r = s >> 5, cb = (s & 31) * 4;
        int n = r0 + r;
        if (n < NN) {
            float4 xv = *(const float4*)&x[(size_t)n * 128 + cb];
            ushort4 t = *(const ushort4*)&tile[r * 136 + cb];
            float4 o = { xv.x + bf2f(t.x), xv.y + bf2f(t.y), xv.z + bf2f(t.z), xv.w + bf2f(t.w) };
            *(float4*)&out[(size_t)n * 128 + cb] = o;
        }
    }
}

extern "C" void kernel_launch(void* const* d_in, const int* in_sizes, int n_in,
                              void* d_out, int out_size, void* d_ws, size_t ws_size,
                              hipStream_t stream) {
    const float* x       = (const float*)d_in[0];
    const int* ei        = (const int*)d_in[1];   // int64 in reference -> int32 from harness
    const float* we0     = (const float*)d_in[2];
    const float* we1     = (const float*)d_in[3];
    const float* wn0     = (const float*)d_in[4];
    const float* wn1     = (const float*)d_in[5];
    float* out           = (float*)d_out;

    char* w = (char*)d_ws;
    size_t off = 0;
    auto alloc = [&](size_t bytes) -> void* {
        off = (off + 255) & ~(size_t)255;
        void* p = w + off;
        off += bytes;
        return p;
    };
    u16*   wcombt = (u16*)alloc(256 * 128 * sizeof(u16));
    u16*   we1t   = (u16*)alloc(128 * 128 * sizeof(u16));
    u16*   wn0t   = (u16*)alloc(128 * 256 * sizeof(u16));
    u16*   wn1t   = (u16*)alloc(128 * 128 * sizeof(u16));
    u16*   p2     = (u16*)alloc((size_t)NN * 256 * sizeof(u16));
    u16*   qb     = (u16*)alloc((size_t)NN * 128 * sizeof(u16));
    u16*   esumx  = (u16*)alloc((size_t)NN * 256 * sizeof(u16));
    int*   cnt    = (int*)alloc((size_t)NN * sizeof(int));
    int*   incl   = (int*)alloc((size_t)NN * sizeof(int));
    int*   offs   = (int*)alloc((size_t)(NN + 1) * sizeof(int));
    int*   cursor = (int*)alloc((size_t)NN * sizeof(int));
    int*   bsum   = (int*)alloc(128 * sizeof(int));
    int*   srcs   = (int*)alloc((size_t)NE * sizeof(int));
    (void)ws_size; (void)in_sizes; (void)n_in; (void)out_size;  // ~68 MB of d_ws used

    hipMemsetAsync(cnt, 0, (size_t)NN * sizeof(int), stream);

    k_wb<<<384, 256, 0, stream>>>(we0, we1, wn0, wn1, wcombt, we1t, wn0t, wn1t);
    k_pq_mfma<<<(NN + 63) / 64, 256, 0, stream>>>(x, wcombt, p2, qb);
    k_hist<<<(NE / 4 + 255) / 256, 256, 0, stream>>>(ei, cnt);
    int nb = (NN + 511) / 512;
    k_scan1<<<nb, 512, 0, stream>>>(cnt, incl, bsum);
    k_scan2<<<1, 128, 0, stream>>>(bsum, nb);
    k_scan3<<<nb, 512, 0, stream>>>(incl, bsum, cnt, offs, cursor);
    k_slots<<<(NE / 4 + 255) / 256, 256, 0, stream>>>(ei, cursor, srcs);
    k_agg<<<(NN + 3) / 4, 256, 0, stream>>>(p2, qb, offs, srcs, esumx);
    k_node_mfma<<<(NN + 63) / 64, 256, 0, stream>>>(x, esumx, we1t, wn0t, wn1t, out);
}

// Round 6
// 269.909 us; speedup vs baseline: 1.0698x; 1.0698x over previous
//
#include <hip/hip_runtime.h>
#include <hip/hip_bf16.h>

// Problem constants (from reference)
#define NN 50000
#define NE 800000
#define HD 128

typedef unsigned short u16;
typedef __attribute__((ext_vector_type(8))) short short8;
typedef __attribute__((ext_vector_type(4))) float floatx4;
#define MFMA __builtin_amdgcn_mfma_f32_16x16x32_bf16

__device__ __forceinline__ float bf2f(u16 v) {
    union { unsigned int u; float f; } x; x.u = ((unsigned int)v) << 16; return x.f;
}
__device__ __forceinline__ u16 f2bf(float f) {
    union { unsigned int u; float f; } x; x.f = f;
    unsigned int r = x.u + 0x7fff + ((x.u >> 16) & 1);
    return (u16)(r >> 16);
}
// fast ELU: t>0 ? t : exp2(t*log2e)-1  (v_exp_f32 path, ~4 instrs)
__device__ __forceinline__ float elu_fast(float t) {
    return t > 0.f ? t : (__builtin_amdgcn_exp2f(t * 1.44269504088896f) - 1.f);
}

// convert 8 consecutive f32 to a bf16 A-fragment
__device__ __forceinline__ short8 cvt8(const float* p) {
    const float4* q = (const float4*)p;
    float4 a = q[0], b = q[1];
    short8 r;
    r[0] = (short)f2bf(a.x); r[1] = (short)f2bf(a.y); r[2] = (short)f2bf(a.z); r[3] = (short)f2bf(a.w);
    r[4] = (short)f2bf(b.x); r[5] = (short)f2bf(b.y); r[6] = (short)f2bf(b.z); r[7] = (short)f2bf(b.w);
    return r;
}

// K0: weight prep -> bf16 transposed layouts [c][k]
__global__ void k_wb(const float* __restrict__ we0, const float* __restrict__ we1,
                     const float* __restrict__ wn0, const float* __restrict__ wn1,
                     u16* __restrict__ wcombt, u16* __restrict__ we1t,
                     u16* __restrict__ wn0t, u16* __restrict__ wn1t) {
    int i = blockIdx.x * 256 + threadIdx.x;
    if (i < 32768) {                       // wcombt
        int c = i >> 7, k = i & 127;
        float v;
        if (c < 128) v = we0[k * 128 + c] + we0[(256 + k) * 128 + c];
        else { int cc = c - 128; v = we0[(128 + k) * 128 + cc] - we0[(256 + k) * 128 + cc]; }
        wcombt[i] = f2bf(v);
    } else if (i < 49152) {                // we1t
        int j = i - 32768; int c = j >> 7, k = j & 127;
        we1t[j] = f2bf(we1[k * 128 + c]);
    } else if (i < 81920) {                // wn0t (k = 0..255)
        int j = i - 49152; int c = j >> 8, k = j & 255;
        wn0t[j] = f2bf(wn0[k * 128 + c]);
    } else if (i < 98304) {                // wn1t
        int j = i - 81920; int c = j >> 7, k = j & 127;
        wn1t[j] = f2bf(wn1[k * 128 + c]);
    }
}

// K2: MFMA [P|Q] = x @ Wcomb. 64 rows/block, 4 waves, LDS-staged coalesced output.
// p2 layout INTERLEAVED quads: p2[n][4i+0,1] = P[2i],P[2i+1] ; p2[n][4i+2,3] = x[2i],x[2i+1] (bf16)
// qb[n][128] = Q ; xb[n][128] = x (bf16, contiguous — for k_node stage-2 A-frags)
__global__ __launch_bounds__(256) void k_pq_mfma(const float* __restrict__ x,
                                                 const u16* __restrict__ wcombt,
                                                 u16* __restrict__ p2, u16* __restrict__ qb,
                                                 u16* __restrict__ xb) {
    __shared__ u16 pq[64 * 264];   // p2 tile, pad 8 u16
    __shared__ u16 qt[64 * 136];   // qb tile, pad 8 u16
    int r0 = blockIdx.x * 64;
    int tid = threadIdx.x, wid = tid >> 6, lane = tid & 63;
    int arow = lane & 15, kblk = lane >> 4;
    // x -> interleaved x-slots of pq tile (+ coalesced bf16 copy to xb)
    for (int s = tid; s < 64 * 64; s += 256) {      // 64 rows x 64 pairs
        int r = s >> 6, i = s & 63;
        int n = r0 + r;
        float2 v = (n < NN) ? *(const float2*)&x[(size_t)n * 128 + 2 * i] : make_float2(0.f, 0.f);
        ushort2 o = { f2bf(v.x), f2bf(v.y) };
        *(ushort2*)&pq[r * 264 + 4 * i + 2] = o;
        if (n < NN) *(ushort2*)&xb[(size_t)n * 128 + 2 * i] = o;
    }
    floatx4 acc[16];
#pragma unroll
    for (int n0 = 0; n0 < 16; n0++) acc[n0] = (floatx4)(0.f);
    int nrow = r0 + wid * 16 + arow; if (nrow >= NN) nrow = NN - 1;
#pragma unroll
    for (int ks = 0; ks < 4; ks++) {
        short8 a = cvt8(&x[(size_t)nrow * 128 + ks * 32 + kblk * 8]);
#pragma unroll
        for (int n0 = 0; n0 < 16; n0++) {
            short8 b = *(const short8*)&wcombt[(size_t)(n0 * 16 + arow) * 128 + ks * 32 + kblk * 8];
            acc[n0] = MFMA(a, b, acc[n0], 0, 0, 0);
        }
    }
    // epilogue into LDS (u16 scatter is cheap in LDS)
#pragma unroll
    for (int n0 = 0; n0 < 16; n0++) {
#pragma unroll
        for (int j = 0; j < 4; j++) {
            int r = wid * 16 + kblk * 4 + j;
            int col = n0 * 16 + arow;
            u16 v = f2bf(acc[n0][j]);
            if (col < 128) pq[r * 264 + 4 * (col >> 1) + (col & 1)] = v;
            else qt[r * 136 + (col - 128)] = v;
        }
    }
    __syncthreads();
    // coalesced flush: p2 (32 short8/row), qb (16 short8/row)
    for (int s = tid; s < 64 * 32; s += 256) {
        int r = s >> 5, cb = (s & 31) * 8;
        int n = r0 + r;
        if (n < NN) *(short8*)&p2[(size_t)n * 256 + cb] = *(const short8*)&pq[r * 264 + cb];
    }
    for (int s = tid; s < 64 * 16; s += 256) {
        int r = s >> 4, cb = (s & 15) * 8;
        int n = r0 + r;
        if (n < NN) *(short8*)&qb[(size_t)n * 128 + cb] = *(const short8*)&qt[r * 136 + cb];
    }
}

// K3: in-degree histogram, 4 edges/thread
__global__ void k_hist(const int* __restrict__ ei, int* __restrict__ cnt) {
    int e = (blockIdx.x * 256 + threadIdx.x) * 4;
    if (e + 4 <= NE) {
        int4 d = *(const int4*)&ei[NE + e];
        atomicAdd(&cnt[d.x], 1); atomicAdd(&cnt[d.y], 1);
        atomicAdd(&cnt[d.z], 1); atomicAdd(&cnt[d.w], 1);
    } else {
        for (int t = e; t < NE; t++) atomicAdd(&cnt[ei[NE + t]], 1);
    }
}

// K4a: per-block (512) inclusive scan
__global__ void k_scan1(const int* __restrict__ cnt, int* __restrict__ incl, int* __restrict__ bsum) {
    __shared__ int s[512];
    int i = blockIdx.x * 512 + threadIdx.x;
    int v = (i < NN) ? cnt[i] : 0;
    s[threadIdx.x] = v; __syncthreads();
    for (int off = 1; off < 512; off <<= 1) {
        int t = (threadIdx.x >= (unsigned)off) ? s[threadIdx.x - off] : 0;
        __syncthreads();
        s[threadIdx.x] += t; __syncthreads();
    }
    if (i < NN) incl[i] = s[threadIdx.x];
    if (threadIdx.x == 511) bsum[blockIdx.x] = s[511];
}

// K4b: exclusive scan of block sums (nb <= 128)
__global__ void k_scan2(int* __restrict__ bsum, int nb) {
    __shared__ int s[128];
    int t = threadIdx.x;
    s[t] = (t < nb) ? bsum[t] : 0;
    __syncthreads();
    if (t == 0) { int run = 0; for (int b = 0; b < nb; b++) { int v = s[b]; s[b] = run; run += v; } }
    __syncthreads();
    if (t < nb) bsum[t] = s[t];
}

// K4c
__global__ void k_scan3(const int* __restrict__ incl, const int* __restrict__ bsum,
                        const int* __restrict__ cnt, int* __restrict__ offs, int* __restrict__ cursor) {
    int i = blockIdx.x * 512 + threadIdx.x;
    if (i < NN) {
        int e = incl[i] + bsum[i >> 9];
        offs[i + 1] = e;
        cursor[i] = e - cnt[i];
        if (i == 0) offs[0] = 0;
    }
}

// K5: scatter edge srcs into CSR slots grouped by dst (4 edges/thread, int4)
__global__ void k_slots(const int* __restrict__ ei, int* __restrict__ cursor, int* __restrict__ srcs) {
    int e = (blockIdx.x * 256 + threadIdx.x) * 4;
    if (e + 4 <= NE) {
        int4 sv = *(const int4*)&ei[e];
        int4 dv = *(const int4*)&ei[NE + e];
        int p0 = atomicAdd(&cursor[dv.x], 1); srcs[p0] = sv.x;
        int p1 = atomicAdd(&cursor[dv.y], 1); srcs[p1] = sv.y;
        int p2_ = atomicAdd(&cursor[dv.z], 1); srcs[p2_] = sv.z;
        int p3 = atomicAdd(&cursor[dv.w], 1); srcs[p3] = sv.w;
    } else {
        for (int t = e; t < NE; t++) {
            int p = atomicAdd(&cursor[ei[NE + t]], 1);
            srcs[p] = ei[t];
        }
    }
}

// K6: one wave per node. Each lane owns channels 2l,2l+1 of BOTH esum and xsum
// via the interleaved p2 quads. Outputs:
//   esumx[n][0:128]   = esum/max(cnt,1)
//   esumx[n][128:256] = (xsum - cnt*x[n])/max(cnt,1)
__global__ __launch_bounds__(256) void k_agg(const u16* __restrict__ p2, const u16* __restrict__ qb,
                                             const int* __restrict__ offs, const int* __restrict__ srcs,
                                             u16* __restrict__ esumx) {
    int wave = threadIdx.x >> 6, lane = threadIdx.x & 63;
    int n = blockIdx.x * 4 + wave;
    if (n >= NN) return;
    int beg = offs[n], end = offs[n + 1];
    ushort2 qv = *(const ushort2*)(qb + (size_t)n * 128 + 2 * lane);
    float q0 = bf2f(qv.x), q1 = bf2f(qv.y);
    float e0 = 0.f, e1 = 0.f, s0 = 0.f, s1 = 0.f;
    int s = beg;
    for (; s + 8 <= end; s += 8) {
        int sr[8];
#pragma unroll
        for (int j = 0; j < 8; j++) sr[j] = srcs[s + j];
        ushort4 v[8];
#pragma unroll
        for (int j = 0; j < 8; j++) v[j] = *(const ushort4*)(p2 + (size_t)sr[j] * 256 + 4 * lane);
#pragma unroll
        for (int j = 0; j < 8; j++) {
            float t0 = bf2f(v[j].x) + q0, t1 = bf2f(v[j].y) + q1;
            e0 += elu_fast(t0); e1 += elu_fast(t1);
            s0 += bf2f(v[j].z); s1 += bf2f(v[j].w);
        }
    }
    for (; s < end; ++s) {
        ushort4 v = *(const ushort4*)(p2 + (size_t)srcs[s] * 256 + 4 * lane);
        float t0 = bf2f(v.x) + q0, t1 = bf2f(v.y) + q1;
        e0 += elu_fast(t0); e1 += elu_fast(t1);
        s0 += bf2f(v.z); s1 += bf2f(v.w);
    }
    float cntf = (float)(end - beg);
    float inv = 1.f / fmaxf(cntf, 1.f);
    ushort2 xo = *(const ushort2*)(p2 + (size_t)n * 256 + 4 * lane + 2);  // own x, ch 2l,2l+1
    s0 = (s0 - cntf * bf2f(xo.x)) * inv;
    s1 = (s1 - cntf * bf2f(xo.y)) * inv;
    e0 *= inv; e1 *= inv;
    ushort2 oe = { f2bf(e0), f2bf(e1) };
    ushort2 os = { f2bf(s0), f2bf(s1) };
    *(ushort2*)(esumx + (size_t)n * 256 + 2 * lane) = oe;
    *(ushort2*)(esumx + (size_t)n * 256 + 128 + 2 * lane) = os;
}

// K7 v3: MFMA node MLP. 128 rows/block, 4 waves; wave wid owns rows wid*32..wid*32+31
// end-to-end (stage + compute + flush), so NO barriers. All global inputs prefetched
// at entry into registers (one latency round-trip instead of a serial chain).
__global__ __launch_bounds__(256, 2) void k_node_mfma(const float* __restrict__ x,
                                                      const u16* __restrict__ xb,
                                                      const u16* __restrict__ esumx,
                                                      const u16* __restrict__ we1t,
                                                      const u16* __restrict__ wn0t,
                                                      const u16* __restrict__ wn1t,
                                                      float* __restrict__ out) {
    __shared__ u16 tile[128 * 136];   // pad 8 u16
    int r0 = blockIdx.x * 128;
    int tid = threadIdx.x, wid = tid >> 6, lane = tid & 63;
    int arow = lane & 15, kblk = lane >> 4;
    int rbase = wid * 32;

    // ---- prefetch ALL global inputs for this wave ----
    int nrow[2];
#pragma unroll
    for (int rt = 0; rt < 2; rt++) {
        int n = r0 + rbase + rt * 16 + arow; if (n >= NN) n = NN - 1;
        nrow[rt] = n;
    }
    short8 stg[8];                                    // xsum' staging: 32 rows x 16 chunks /64 lanes
#pragma unroll
    for (int t = 0; t < 8; t++) {
        int idx = t * 64 + lane;
        int r = idx >> 4, cb = (idx & 15) * 8;
        int n = r0 + rbase + r; if (n >= NN) n = NN - 1;
        stg[t] = *(const short8*)&esumx[(size_t)n * 256 + 128 + cb];
    }
    short8 a1[2][4], ax[2][4];                        // stage-1 esum frags + stage-2 x frags
#pragma unroll
    for (int rt = 0; rt < 2; rt++)
#pragma unroll
        for (int ks = 0; ks < 4; ks++) {
            a1[rt][ks] = *(const short8*)&esumx[(size_t)nrow[rt] * 256 + ks * 32 + kblk * 8];
            ax[rt][ks] = *(const short8*)&xb[(size_t)nrow[rt] * 128 + ks * 32 + kblk * 8];
        }
    // xsum' -> LDS (own rows only)
#pragma unroll
    for (int t = 0; t < 8; t++) {
        int idx = t * 64 + lane;
        int r = rbase + (idx >> 4), cb = (idx & 15) * 8;
        *(short8*)&tile[r * 136 + cb] = stg[t];
    }
    // ---- stage 1: T = esum' @ We1 ----
    floatx4 acc[2][8];
#pragma unroll
    for (int rt = 0; rt < 2; rt++)
#pragma unroll
        for (int n0 = 0; n0 < 8; n0++) acc[rt][n0] = (floatx4)(0.f);
#pragma unroll
    for (int ks = 0; ks < 4; ks++)
#pragma unroll
        for (int n0 = 0; n0 < 8; n0++) {
            short8 b = *(const short8*)&we1t[(size_t)(n0 * 16 + arow) * 128 + ks * 32 + kblk * 8];
            acc[0][n0] = MFMA(a1[0][ks], b, acc[0][n0], 0, 0, 0);
            acc[1][n0] = MFMA(a1[1][ks], b, acc[1][n0], 0, 0, 0);
        }
    // ---- m = T + xsum' (own rows, in place; within-wave LDS RAW ordering) ----
#pragma unroll
    for (int rt = 0; rt < 2; rt++)
#pragma unroll
        for (int n0 = 0; n0 < 8; n0++)
#pragma unroll
            for (int j = 0; j < 4; j++) {
                int rloc = rbase + rt * 16 + kblk * 4 + j;
                int col = n0 * 16 + arow;
                float m = acc[rt][n0][j] + bf2f(tile[rloc * 136 + col]);
                tile[rloc * 136 + col] = f2bf(m);
            }
    // ---- stage 2: h = ELU(x@Wn0a + m@Wn0b) ----
#pragma unroll
    for (int rt = 0; rt < 2; rt++)
#pragma unroll
        for (int n0 = 0; n0 < 8; n0++) acc[rt][n0] = (floatx4)(0.f);
#pragma unroll
    for (int ks = 0; ks < 4; ks++) {
        short8 am[2];
#pragma unroll
        for (int rt = 0; rt < 2; rt++)
            am[rt] = *(const short8*)&tile[(rbase + rt * 16 + arow) * 136 + ks * 32 + kblk * 8];
#pragma unroll
        for (int n0 = 0; n0 < 8; n0++) {
            short8 bx = *(const short8*)&wn0t[(size_t)(n0 * 16 + arow) * 256 + ks * 32 + kblk * 8];
            short8 bm = *(const short8*)&wn0t[(size_t)(n0 * 16 + arow) * 256 + 128 + ks * 32 + kblk * 8];
#pragma unroll
            for (int rt = 0; rt < 2; rt++) {
                acc[rt][n0] = MFMA(ax[rt][ks], bx, acc[rt][n0], 0, 0, 0);
                acc[rt][n0] = MFMA(am[rt], bm, acc[rt][n0], 0, 0, 0);
            }
        }
    }
    // ---- h -> tile (own rows) ----
#pragma unroll
    for (int rt = 0; rt < 2; rt++)
#pragma unroll
        for (int n0 = 0; n0 < 8; n0++)
#pragma unroll
            for (int j = 0; j < 4; j++) {
                int rloc = rbase + rt * 16 + kblk * 4 + j;
                tile[rloc * 136 + n0 * 16 + arow] = f2bf(elu_fast(acc[rt][n0][j]));
            }
    // ---- stage 3: r = h @ Wn1 ----
#pragma unroll
    for (int rt = 0; rt < 2; rt++)
#pragma unroll
        for (int n0 = 0; n0 < 8; n0++) acc[rt][n0] = (floatx4)(0.f);
#pragma unroll
    for (int ks = 0; ks < 4; ks++) {
        short8 a[2];
#pragma unroll
        for (int rt = 0; rt < 2; rt++)
            a[rt] = *(const short8*)&tile[(rbase + rt * 16 + arow) * 136 + ks * 32 + kblk * 8];
#pragma unroll
        for (int n0 = 0; n0 < 8; n0++) {
            short8 b = *(const short8*)&wn1t[(size_t)(n0 * 16 + arow) * 128 + ks * 32 + kblk * 8];
            acc[0][n0] = MFMA(a[0], b, acc[0][n0], 0, 0, 0);
            acc[1][n0] = MFMA(a[1], b, acc[1][n0], 0, 0, 0);
        }
    }
    // ---- r -> tile (bf16), per-wave coalesced float4 epilogue ----
#pragma unroll
    for (int rt = 0; rt < 2; rt++)
#pragma unroll
        for (int n0 = 0; n0 < 8; n0++)
#pragma unroll
            for (int j = 0; j < 4; j++)
                tile[(rbase + rt * 16 + kblk * 4 + j) * 136 + n0 * 16 + arow] = f2bf(acc[rt][n0][j]);
#pragma unroll
    for (int t = 0; t < 16; t++) {
        int idx = t * 64 + lane;                 // 32 rows x 32 float4-chunks
        int r = idx >> 5, cb = (idx & 31) * 4;
        int n = r0 + rbase + r;
        if (n < NN) {
            float4 xv = *(const float4*)&x[(size_t)n * 128 + cb];
            ushort4 tv = *(const ushort4*)&tile[(rbase + r) * 136 + cb];
            float4 o = { xv.x + bf2f(tv.x), xv.y + bf2f(tv.y), xv.z + bf2f(tv.z), xv.w + bf2f(tv.w) };
            *(float4*)&out[(size_t)n * 128 + cb] = o;
        }
    }
}

extern "C" void kernel_launch(void* const* d_in, const int* in_sizes, int n_in,
                              void* d_out, int out_size, void* d_ws, size_t ws_size,
                              hipStream_t stream) {
    const float* x       = (const float*)d_in[0];
    const int* ei        = (const int*)d_in[1];   // int64 in reference -> int32 from harness
    const float* we0     = (const float*)d_in[2];
    const float* we1     = (const float*)d_in[3];
    const float* wn0     = (const float*)d_in[4];
    const float* wn1     = (const float*)d_in[5];
    float* out           = (float*)d_out;

    char* w = (char*)d_ws;
    size_t off = 0;
    auto alloc = [&](size_t bytes) -> void* {
        off = (off + 255) & ~(size_t)255;
        void* p = w + off;
        off += bytes;
        return p;
    };
    u16*   wcombt = (u16*)alloc(256 * 128 * sizeof(u16));
    u16*   we1t   = (u16*)alloc(128 * 128 * sizeof(u16));
    u16*   wn0t   = (u16*)alloc(128 * 256 * sizeof(u16));
    u16*   wn1t   = (u16*)alloc(128 * 128 * sizeof(u16));
    u16*   p2     = (u16*)alloc((size_t)NN * 256 * sizeof(u16));
    u16*   qb     = (u16*)alloc((size_t)NN * 128 * sizeof(u16));
    u16*   xb     = (u16*)alloc((size_t)NN * 128 * sizeof(u16));
    u16*   esumx  = (u16*)alloc((size_t)NN * 256 * sizeof(u16));
    int*   cnt    = (int*)alloc((size_t)NN * sizeof(int));
    int*   incl   = (int*)alloc((size_t)NN * sizeof(int));
    int*   offs   = (int*)alloc((size_t)(NN + 1) * sizeof(int));
    int*   cursor = (int*)alloc((size_t)NN * sizeof(int));
    int*   bsum   = (int*)alloc(128 * sizeof(int));
    int*   srcs   = (int*)alloc((size_t)NE * sizeof(int));
    (void)ws_size; (void)in_sizes; (void)n_in; (void)out_size;  // ~81 MB of d_ws used

    hipMemsetAsync(cnt, 0, (size_t)NN * sizeof(int), stream);

    k_wb<<<384, 256, 0, stream>>>(we0, we1, wn0, wn1, wcombt, we1t, wn0t, wn1t);
    k_pq_mfma<<<(NN + 63) / 64, 256, 0, stream>>>(x, wcombt, p2, qb, xb);
    k_hist<<<(NE / 4 + 255) / 256, 256, 0, stream>>>(ei, cnt);
    int nb = (NN + 511) / 512;
    k_scan1<<<nb, 512, 0, stream>>>(cnt, incl, bsum);
    k_scan2<<<1, 128, 0, stream>>>(bsum, nb);
    k_scan3<<<nb, 512, 0, stream>>>(incl, bsum, cnt, offs, cursor);
    k_slots<<<(NE / 4 + 255) / 256, 256, 0, stream>>>(ei, cursor, srcs);
    k_agg<<<(NN + 3) / 4, 256, 0, stream>>>(p2, qb, offs, srcs, esumx);
    k_node_mfma<<<(NN + 127) / 128, 256, 0, stream>>>(x, xb, esumx, we1t, wn0t, wn1t, out);
}

// Round 7
// 251.247 us; speedup vs baseline: 1.1493x; 1.0743x over previous
//
#include <hip/hip_runtime.h>
#include <hip/hip_bf16.h>

// Problem constants (from reference)
#define NN 50000
#define NE 800000
#define HD 128

typedef unsigned short u16;
typedef __attribute__((ext_vector_type(8))) short short8;
typedef __attribute__((ext_vector_type(4))) float floatx4;
#define MFMA __builtin_amdgcn_mfma_f32_16x16x32_bf16

__device__ __forceinline__ float bf2f(u16 v) {
    union { unsigned int u; float f; } x; x.u = ((unsigned int)v) << 16; return x.f;
}
__device__ __forceinline__ u16 f2bf(float f) {
    union { unsigned int u; float f; } x; x.f = f;
    unsigned int r = x.u + 0x7fff + ((x.u >> 16) & 1);
    return (u16)(r >> 16);
}
// fast ELU: t>0 ? t : exp2(t*log2e)-1  (v_exp_f32 path, ~4 instrs)
__device__ __forceinline__ float elu_fast(float t) {
    return t > 0.f ? t : (__builtin_amdgcn_exp2f(t * 1.44269504088896f) - 1.f);
}

// convert 8 consecutive f32 to a bf16 A-fragment
__device__ __forceinline__ short8 cvt8(const float* p) {
    const float4* q = (const float4*)p;
    float4 a = q[0], b = q[1];
    short8 r;
    r[0] = (short)f2bf(a.x); r[1] = (short)f2bf(a.y); r[2] = (short)f2bf(a.z); r[3] = (short)f2bf(a.w);
    r[4] = (short)f2bf(b.x); r[5] = (short)f2bf(b.y); r[6] = (short)f2bf(b.z); r[7] = (short)f2bf(b.w);
    return r;
}

// K0: weight prep -> bf16 transposed layouts [c][k]; also zeroes cnt (fused memset)
__global__ void k_wb(const float* __restrict__ we0, const float* __restrict__ we1,
                     const float* __restrict__ wn0, const float* __restrict__ wn1,
                     u16* __restrict__ wcombt, u16* __restrict__ we1t,
                     u16* __restrict__ wn0t, u16* __restrict__ wn1t,
                     int* __restrict__ cnt) {
    int i = blockIdx.x * 256 + threadIdx.x;
    if (i < 32768) {                       // wcombt
        int c = i >> 7, k = i & 127;
        float v;
        if (c < 128) v = we0[k * 128 + c] + we0[(256 + k) * 128 + c];
        else { int cc = c - 128; v = we0[(128 + k) * 128 + cc] - we0[(256 + k) * 128 + cc]; }
        wcombt[i] = f2bf(v);
    } else if (i < 49152) {                // we1t
        int j = i - 32768; int c = j >> 7, k = j & 127;
        we1t[j] = f2bf(we1[k * 128 + c]);
    } else if (i < 81920) {                // wn0t (k = 0..255)
        int j = i - 49152; int c = j >> 8, k = j & 255;
        wn0t[j] = f2bf(wn0[k * 128 + c]);
    } else if (i < 98304) {                // wn1t
        int j = i - 81920; int c = j >> 7, k = j & 127;
        wn1t[j] = f2bf(wn1[k * 128 + c]);
    } else if (i < 98304 + NN) {           // cnt = 0
        cnt[i - 98304] = 0;
    }
}

// K2 v4: MFMA [P|Q] = x @ Wcomb. 32 rows/block, 4 waves = (2 row-tiles x 2 col-halves).
// p2 layout INTERLEAVED quads: p2[n][4i+0,1] = P[2i],P[2i+1] ; p2[n][4i+2,3] = x[2i],x[2i+1] (bf16)
// qb[n][128] = Q ; xb[n][128] = x (bf16, contiguous — for k_node stage-2 A-frags)
__global__ __launch_bounds__(256) void k_pq_mfma(const float* __restrict__ x,
                                                 const u16* __restrict__ wcombt,
                                                 u16* __restrict__ p2, u16* __restrict__ qb,
                                                 u16* __restrict__ xb) {
    __shared__ u16 pq[32 * 264];   // P|x interleave tile, pad 8 u16
    __shared__ u16 qt[32 * 136];   // Q tile, pad 8 u16
    int r0 = blockIdx.x * 32;
    int tid = threadIdx.x, wid = tid >> 6, lane = tid & 63;
    int arow = lane & 15, kblk = lane >> 4;
    int rw = (wid & 1) * 16;            // row-tile offset (local)
    int ch = (wid >> 1) * 128;          // output-channel half
    // x -> interleaved x-slots of pq tile (+ coalesced bf16 copy to xb)
    for (int s = tid; s < 32 * 64; s += 256) {      // 32 rows x 64 pairs
        int r = s >> 6, i = s & 63;
        int n = r0 + r;
        float2 v = (n < NN) ? *(const float2*)&x[(size_t)n * 128 + 2 * i] : make_float2(0.f, 0.f);
        ushort2 o = { f2bf(v.x), f2bf(v.y) };
        *(ushort2*)&pq[r * 264 + 4 * i + 2] = o;
        if (n < NN) *(ushort2*)&xb[(size_t)n * 128 + 2 * i] = o;
    }
    floatx4 acc[8];
#pragma unroll
    for (int n0 = 0; n0 < 8; n0++) acc[n0] = (floatx4)(0.f);
    int nrow = r0 + rw + arow; if (nrow >= NN) nrow = NN - 1;
#pragma unroll
    for (int ks = 0; ks < 4; ks++) {
        short8 a = cvt8(&x[(size_t)nrow * 128 + ks * 32 + kblk * 8]);
#pragma unroll
        for (int n0 = 0; n0 < 8; n0++) {
            short8 b = *(const short8*)&wcombt[(size_t)(ch + n0 * 16 + arow) * 128 + ks * 32 + kblk * 8];
            acc[n0] = MFMA(a, b, acc[n0], 0, 0, 0);
        }
    }
    // epilogue into LDS (branch-free: col-half is wave-uniform)
#pragma unroll
    for (int n0 = 0; n0 < 8; n0++) {
#pragma unroll
        for (int j = 0; j < 4; j++) {
            int r = rw + kblk * 4 + j;
            int col = ch + n0 * 16 + arow;
            u16 v = f2bf(acc[n0][j]);
            if (ch == 0) pq[r * 264 + 4 * (col >> 1) + (col & 1)] = v;
            else qt[r * 136 + (col - 128)] = v;
        }
    }
    __syncthreads();
    // coalesced flush: p2 (32 short8/row), qb (16 short8/row)
    for (int s = tid; s < 32 * 32; s += 256) {
        int r = s >> 5, cb = (s & 31) * 8;
        int n = r0 + r;
        if (n < NN) *(short8*)&p2[(size_t)n * 256 + cb] = *(const short8*)&pq[r * 264 + cb];
    }
    for (int s = tid; s < 32 * 16; s += 256) {
        int r = s >> 4, cb = (s & 15) * 8;
        int n = r0 + r;
        if (n < NN) *(short8*)&qb[(size_t)n * 128 + cb] = *(const short8*)&qt[r * 136 + cb];
    }
}

// K3: in-degree histogram, 4 edges/thread
__global__ void k_hist(const int* __restrict__ ei, int* __restrict__ cnt) {
    int e = (blockIdx.x * 256 + threadIdx.x) * 4;
    if (e + 4 <= NE) {
        int4 d = *(const int4*)&ei[NE + e];
        atomicAdd(&cnt[d.x], 1); atomicAdd(&cnt[d.y], 1);
        atomicAdd(&cnt[d.z], 1); atomicAdd(&cnt[d.w], 1);
    } else {
        for (int t = e; t < NE; t++) atomicAdd(&cnt[ei[NE + t]], 1);
    }
}

// K4a: per-block (512) inclusive scan
__global__ void k_scan1(const int* __restrict__ cnt, int* __restrict__ incl, int* __restrict__ bsum) {
    __shared__ int s[512];
    int i = blockIdx.x * 512 + threadIdx.x;
    int v = (i < NN) ? cnt[i] : 0;
    s[threadIdx.x] = v; __syncthreads();
    for (int off = 1; off < 512; off <<= 1) {
        int t = (threadIdx.x >= (unsigned)off) ? s[threadIdx.x - off] : 0;
        __syncthreads();
        s[threadIdx.x] += t; __syncthreads();
    }
    if (i < NN) incl[i] = s[threadIdx.x];
    if (threadIdx.x == 511) bsum[blockIdx.x] = s[511];
}

// K4b: exclusive scan of block sums (nb <= 128)
__global__ void k_scan2(int* __restrict__ bsum, int nb) {
    __shared__ int s[128];
    int t = threadIdx.x;
    s[t] = (t < nb) ? bsum[t] : 0;
    __syncthreads();
    if (t == 0) { int run = 0; for (int b = 0; b < nb; b++) { int v = s[b]; s[b] = run; run += v; } }
    __syncthreads();
    if (t < nb) bsum[t] = s[t];
}

// K4c
__global__ void k_scan3(const int* __restrict__ incl, const int* __restrict__ bsum,
                        const int* __restrict__ cnt, int* __restrict__ offs, int* __restrict__ cursor) {
    int i = blockIdx.x * 512 + threadIdx.x;
    if (i < NN) {
        int e = incl[i] + bsum[i >> 9];
        offs[i + 1] = e;
        cursor[i] = e - cnt[i];
        if (i == 0) offs[0] = 0;
    }
}

// K5: scatter edge srcs into CSR slots grouped by dst (4 edges/thread, int4)
__global__ void k_slots(const int* __restrict__ ei, int* __restrict__ cursor, int* __restrict__ srcs) {
    int e = (blockIdx.x * 256 + threadIdx.x) * 4;
    if (e + 4 <= NE) {
        int4 sv = *(const int4*)&ei[e];
        int4 dv = *(const int4*)&ei[NE + e];
        int p0 = atomicAdd(&cursor[dv.x], 1); srcs[p0] = sv.x;
        int p1 = atomicAdd(&cursor[dv.y], 1); srcs[p1] = sv.y;
        int p2_ = atomicAdd(&cursor[dv.z], 1); srcs[p2_] = sv.z;
        int p3 = atomicAdd(&cursor[dv.w], 1); srcs[p3] = sv.w;
    } else {
        for (int t = e; t < NE; t++) {
            int p = atomicAdd(&cursor[ei[NE + t]], 1);
            srcs[p] = ei[t];
        }
    }
}

// K6 v3: one wave per node, masked 8-batches (no serial tail) + index prefetch pipeline.
// Each lane owns channels 2l,2l+1 of BOTH esum and xsum via interleaved p2 quads.
//   esumx[n][0:128]   = esum/max(cnt,1)
//   esumx[n][128:256] = (xsum - cnt*x[n])/max(cnt,1)
__global__ __launch_bounds__(256) void k_agg(const u16* __restrict__ p2, const u16* __restrict__ qb,
                                             const int* __restrict__ offs, const int* __restrict__ srcs,
                                             u16* __restrict__ esumx) {
    int wave = threadIdx.x >> 6, lane = threadIdx.x & 63;
    int n = blockIdx.x * 4 + wave;
    if (n >= NN) return;
    int beg = offs[n], end = offs[n + 1];
    ushort2 qv = *(const ushort2*)(qb + (size_t)n * 128 + 2 * lane);
    float q0 = bf2f(qv.x), q1 = bf2f(qv.y);
    float e0 = 0.f, e1 = 0.f, s0 = 0.f, s1 = 0.f;
    if (end > beg) {
        int last = end - 1;
        int sr[8];
#pragma unroll
        for (int j = 0; j < 8; j++) { int t = beg + j; sr[j] = srcs[t < end ? t : last]; }
        for (int base = beg; base < end; base += 8) {
            ushort4 v[8];
#pragma unroll
            for (int j = 0; j < 8; j++) v[j] = *(const ushort4*)(p2 + (size_t)sr[j] * 256 + 4 * lane);
            int nbase = base + 8;
            if (nbase < end) {                 // prefetch next batch's indices during compute
#pragma unroll
                for (int j = 0; j < 8; j++) { int t = nbase + j; sr[j] = srcs[t < end ? t : last]; }
            }
#pragma unroll
            for (int j = 0; j < 8; j++) {
                bool live = (base + j < end);  // wave-uniform
                float t0 = bf2f(v[j].x) + q0, t1 = bf2f(v[j].y) + q1;
                float c0 = elu_fast(t0), c1 = elu_fast(t1);
                e0 += live ? c0 : 0.f;
                e1 += live ? c1 : 0.f;
                s0 += live ? bf2f(v[j].z) : 0.f;
                s1 += live ? bf2f(v[j].w) : 0.f;
            }
        }
    }
    float cntf = (float)(end - beg);
    float inv = 1.f / fmaxf(cntf, 1.f);
    ushort2 xo = *(const ushort2*)(p2 + (size_t)n * 256 + 4 * lane + 2);  // own x, ch 2l,2l+1
    s0 = (s0 - cntf * bf2f(xo.x)) * inv;
    s1 = (s1 - cntf * bf2f(xo.y)) * inv;
    e0 *= inv; e1 *= inv;
    ushort2 oe = { f2bf(e0), f2bf(e1) };
    ushort2 os = { f2bf(s0), f2bf(s1) };
    *(ushort2*)(esumx + (size_t)n * 256 + 2 * lane) = oe;
    *(ushort2*)(esumx + (size_t)n * 256 + 128 + 2 * lane) = os;
}

// K7 v3: MFMA node MLP. 128 rows/block, 4 waves; wave wid owns rows wid*32..wid*32+31
// end-to-end (stage + compute + flush), so NO barriers. All global inputs prefetched
// at entry into registers (one latency round-trip instead of a serial chain).
__global__ __launch_bounds__(256, 2) void k_node_mfma(const float* __restrict__ x,
                                                      const u16* __restrict__ xb,
                                                      const u16* __restrict__ esumx,
                                                      const u16* __restrict__ we1t,
                                                      const u16* __restrict__ wn0t,
                                                      const u16* __restrict__ wn1t,
                                                      float* __restrict__ out) {
    __shared__ u16 tile[128 * 136];   // pad 8 u16
    int r0 = blockIdx.x * 128;
    int tid = threadIdx.x, wid = tid >> 6, lane = tid & 63;
    int arow = lane & 15, kblk = lane >> 4;
    int rbase = wid * 32;

    // ---- prefetch ALL global inputs for this wave ----
    int nrow[2];
#pragma unroll
    for (int rt = 0; rt < 2; rt++) {
        int n = r0 + rbase + rt * 16 + arow; if (n >= NN) n = NN - 1;
        nrow[rt] = n;
    }
    short8 stg[8];                                    // xsum' staging: 32 rows x 16 chunks /64 lanes
#pragma unroll
    for (int t = 0; t < 8; t++) {
        int idx = t * 64 + lane;
        int r = idx >> 4, cb = (idx & 15) * 8;
        int n = r0 + rbase + r; if (n >= NN) n = NN - 1;
        stg[t] = *(const short8*)&esumx[(size_t)n * 256 + 128 + cb];
    }
    short8 a1[2][4], ax[2][4];                        // stage-1 esum frags + stage-2 x frags
#pragma unroll
    for (int rt = 0; rt < 2; rt++)
#pragma unroll
        for (int ks = 0; ks < 4; ks++) {
            a1[rt][ks] = *(const short8*)&esumx[(size_t)nrow[rt] * 256 + ks * 32 + kblk * 8];
            ax[rt][ks] = *(const short8*)&xb[(size_t)nrow[rt] * 128 + ks * 32 + kblk * 8];
        }
    // xsum' -> LDS (own rows only)
#pragma unroll
    for (int t = 0; t < 8; t++) {
        int idx = t * 64 + lane;
        int r = rbase + (idx >> 4), cb = (idx & 15) * 8;
        *(short8*)&tile[r * 136 + cb] = stg[t];
    }
    // ---- stage 1: T = esum' @ We1 ----
    floatx4 acc[2][8];
#pragma unroll
    for (int rt = 0; rt < 2; rt++)
#pragma unroll
        for (int n0 = 0; n0 < 8; n0++) acc[rt][n0] = (floatx4)(0.f);
#pragma unroll
    for (int ks = 0; ks < 4; ks++)
#pragma unroll
        for (int n0 = 0; n0 < 8; n0++) {
            short8 b = *(const short8*)&we1t[(size_t)(n0 * 16 + arow) * 128 + ks * 32 + kblk * 8];
            acc[0][n0] = MFMA(a1[0][ks], b, acc[0][n0], 0, 0, 0);
            acc[1][n0] = MFMA(a1[1][ks], b, acc[1][n0], 0, 0, 0);
        }
    // ---- m = T + xsum' (own rows, in place; within-wave LDS RAW ordering) ----
#pragma unroll
    for (int rt = 0; rt < 2; rt++)
#pragma unroll
        for (int n0 = 0; n0 < 8; n0++)
#pragma unroll
            for (int j = 0; j < 4; j++) {
                int rloc = rbase + rt * 16 + kblk * 4 + j;
                int col = n0 * 16 + arow;
                float m = acc[rt][n0][j] + bf2f(tile[rloc * 136 + col]);
                tile[rloc * 136 + col] = f2bf(m);
            }
    // ---- stage 2: h = ELU(x@Wn0a + m@Wn0b) ----
#pragma unroll
    for (int rt = 0; rt < 2; rt++)
#pragma unroll
        for (int n0 = 0; n0 < 8; n0++) acc[rt][n0] = (floatx4)(0.f);
#pragma unroll
    for (int ks = 0; ks < 4; ks++) {
        short8 am[2];
#pragma unroll
        for (int rt = 0; rt < 2; rt++)
            am[rt] = *(const short8*)&tile[(rbase + rt * 16 + arow) * 136 + ks * 32 + kblk * 8];
#pragma unroll
        for (int n0 = 0; n0 < 8; n0++) {
            short8 bx = *(const short8*)&wn0t[(size_t)(n0 * 16 + arow) * 256 + ks * 32 + kblk * 8];
            short8 bm = *(const short8*)&wn0t[(size_t)(n0 * 16 + arow) * 256 + 128 + ks * 32 + kblk * 8];
#pragma unroll
            for (int rt = 0; rt < 2; rt++) {
                acc[rt][n0] = MFMA(ax[rt][ks], bx, acc[rt][n0], 0, 0, 0);
                acc[rt][n0] = MFMA(am[rt], bm, acc[rt][n0], 0, 0, 0);
            }
        }
    }
    // ---- h -> tile (own rows) ----
#pragma unroll
    for (int rt = 0; rt < 2; rt++)
#pragma unroll
        for (int n0 = 0; n0 < 8; n0++)
#pragma unroll
            for (int j = 0; j < 4; j++) {
                int rloc = rbase + rt * 16 + kblk * 4 + j;
                tile[rloc * 136 + n0 * 16 + arow] = f2bf(elu_fast(acc[rt][n0][j]));
            }
    // ---- stage 3: r = h @ Wn1 ----
#pragma unroll
    for (int rt = 0; rt < 2; rt++)
#pragma unroll
        for (int n0 = 0; n0 < 8; n0++) acc[rt][n0] = (floatx4)(0.f);
#pragma unroll
    for (int ks = 0; ks < 4; ks++) {
        short8 a[2];
#pragma unroll
        for (int rt = 0; rt < 2; rt++)
            a[rt] = *(const short8*)&tile[(rbase + rt * 16 + arow) * 136 + ks * 32 + kblk * 8];
#pragma unroll
        for (int n0 = 0; n0 < 8; n0++) {
            short8 b = *(const short8*)&wn1t[(size_t)(n0 * 16 + arow) * 128 + ks * 32 + kblk * 8];
            acc[0][n0] = MFMA(a[0], b, acc[0][n0], 0, 0, 0);
            acc[1][n0] = MFMA(a[1], b, acc[1][n0], 0, 0, 0);
        }
    }
    // ---- r -> tile (bf16), per-wave coalesced float4 epilogue ----
#pragma unroll
    for (int rt = 0; rt < 2; rt++)
#pragma unroll
        for (int n0 = 0; n0 < 8; n0++)
#pragma unroll
            for (int j = 0; j < 4; j++)
                tile[(rbase + rt * 16 + kblk * 4 + j) * 136 + n0 * 16 + arow] = f2bf(acc[rt][n0][j]);
#pragma unroll
    for (int t = 0; t < 16; t++) {
        int idx = t * 64 + lane;                 // 32 rows x 32 float4-chunks
        int r = idx >> 5, cb = (idx & 31) * 4;
        int n = r0 + rbase + r;
        if (n < NN) {
            float4 xv = *(const float4*)&x[(size_t)n * 128 + cb];
            ushort4 tv = *(const ushort4*)&tile[(rbase + r) * 136 + cb];
            float4 o = { xv.x + bf2f(tv.x), xv.y + bf2f(tv.y), xv.z + bf2f(tv.z), xv.w + bf2f(tv.w) };
            *(float4*)&out[(size_t)n * 128 + cb] = o;
        }
    }
}

extern "C" void kernel_launch(void* const* d_in, const int* in_sizes, int n_in,
                              void* d_out, int out_size, void* d_ws, size_t ws_size,
                              hipStream_t stream) {
    const float* x       = (const float*)d_in[0];
    const int* ei        = (const int*)d_in[1];   // int64 in reference -> int32 from harness
    const float* we0     = (const float*)d_in[2];
    const float* we1     = (const float*)d_in[3];
    const float* wn0     = (const float*)d_in[4];
    const float* wn1     = (const float*)d_in[5];
    float* out           = (float*)d_out;

    char* w = (char*)d_ws;
    size_t off = 0;
    auto alloc = [&](size_t bytes) -> void* {
        off = (off + 255) & ~(size_t)255;
        void* p = w + off;
        off += bytes;
        return p;
    };
    u16*   wcombt = (u16*)alloc(256 * 128 * sizeof(u16));
    u16*   we1t   = (u16*)alloc(128 * 128 * sizeof(u16));
    u16*   wn0t   = (u16*)alloc(128 * 256 * sizeof(u16));
    u16*   wn1t   = (u16*)alloc(128 * 128 * sizeof(u16));
    u16*   p2     = (u16*)alloc((size_t)NN * 256 * sizeof(u16));
    u16*   qb     = (u16*)alloc((size_t)NN * 128 * sizeof(u16));
    u16*   xb     = (u16*)alloc((size_t)NN * 128 * sizeof(u16));
    u16*   esumx  = (u16*)alloc((size_t)NN * 256 * sizeof(u16));
    int*   cnt    = (int*)alloc((size_t)NN * sizeof(int));
    int*   incl   = (int*)alloc((size_t)NN * sizeof(int));
    int*   offs   = (int*)alloc((size_t)(NN + 1) * sizeof(int));
    int*   cursor = (int*)alloc((size_t)NN * sizeof(int));
    int*   bsum   = (int*)alloc(128 * sizeof(int));
    int*   srcs   = (int*)alloc((size_t)NE * sizeof(int));
    (void)ws_size; (void)in_sizes; (void)n_in; (void)out_size;  // ~81 MB of d_ws used

    k_wb<<<(98304 + NN + 255) / 256, 256, 0, stream>>>(we0, we1, wn0, wn1,
                                                       wcombt, we1t, wn0t, wn1t, cnt);
    k_pq_mfma<<<(NN + 31) / 32, 256, 0, stream>>>(x, wcombt, p2, qb, xb);
    k_hist<<<(NE / 4 + 255) / 256, 256, 0, stream>>>(ei, cnt);
    int nb = (NN + 511) / 512;
    k_scan1<<<nb, 512, 0, stream>>>(cnt, incl, bsum);
    k_scan2<<<1, 128, 0, stream>>>(bsum, nb);
    k_scan3<<<nb, 512, 0, stream>>>(incl, bsum, cnt, offs, cursor);
    k_slots<<<(NE / 4 + 255) / 256, 256, 0, stream>>>(ei, cursor, srcs);
    k_agg<<<(NN + 3) / 4, 256, 0, stream>>>(p2, qb, offs, srcs, esumx);
    k_node_mfma<<<(NN + 127) / 128, 256, 0, stream>>>(x, xb, esumx, we1t, wn0t, wn1t, out);
}

// Round 8
// 228.589 us; speedup vs baseline: 1.2632x; 1.0991x over previous
//
#include <hip/hip_runtime.h>
#include <hip/hip_bf16.h>

// Problem constants (from reference)
#define NN 50000
#define NE 800000
#define HD 128

typedef unsigned short u16;
typedef unsigned char u8;
typedef unsigned int u32;
typedef __attribute__((ext_vector_type(8))) short short8;
typedef __attribute__((ext_vector_type(4))) float floatx4;
typedef __attribute__((ext_vector_type(2))) float f32x2;
#define MFMA __builtin_amdgcn_mfma_f32_16x16x32_bf16

__device__ __forceinline__ float bf2f(u16 v) {
    union { unsigned int u; float f; } x; x.u = ((unsigned int)v) << 16; return x.f;
}
__device__ __forceinline__ u16 f2bf(float f) {
    union { unsigned int u; float f; } x; x.f = f;
    unsigned int r = x.u + 0x7fff + ((x.u >> 16) & 1);
    return (u16)(r >> 16);
}
// fast ELU: t>0 ? t : exp2(t*log2e)-1  (v_exp_f32 path, ~4 instrs)
__device__ __forceinline__ float elu_fast(float t) {
    return t > 0.f ? t : (__builtin_amdgcn_exp2f(t * 1.44269504088896f) - 1.f);
}
// pack 2 f32 -> 2 fp8 (e4m3) in low 16 bits
__device__ __forceinline__ u32 pk_fp8(float a, float b) {
    return __builtin_amdgcn_cvt_pk_fp8_f32(a, b, 0u, false);
}

// convert 8 consecutive f32 to a bf16 A-fragment
__device__ __forceinline__ short8 cvt8(const float* p) {
    const float4* q = (const float4*)p;
    float4 a = q[0], b = q[1];
    short8 r;
    r[0] = (short)f2bf(a.x); r[1] = (short)f2bf(a.y); r[2] = (short)f2bf(a.z); r[3] = (short)f2bf(a.w);
    r[4] = (short)f2bf(b.x); r[5] = (short)f2bf(b.y); r[6] = (short)f2bf(b.z); r[7] = (short)f2bf(b.w);
    return r;
}

// K0: weight prep -> bf16 transposed layouts [c][k]; also zeroes cnt (fused memset)
__global__ void k_wb(const float* __restrict__ we0, const float* __restrict__ we1,
                     const float* __restrict__ wn0, const float* __restrict__ wn1,
                     u16* __restrict__ wcombt, u16* __restrict__ we1t,
                     u16* __restrict__ wn0t, u16* __restrict__ wn1t,
                     int* __restrict__ cnt) {
    int i = blockIdx.x * 256 + threadIdx.x;
    if (i < 32768) {                       // wcombt
        int c = i >> 7, k = i & 127;
        float v;
        if (c < 128) v = we0[k * 128 + c] + we0[(256 + k) * 128 + c];
        else { int cc = c - 128; v = we0[(128 + k) * 128 + cc] - we0[(256 + k) * 128 + cc]; }
        wcombt[i] = f2bf(v);
    } else if (i < 49152) {                // we1t
        int j = i - 32768; int c = j >> 7, k = j & 127;
        we1t[j] = f2bf(we1[k * 128 + c]);
    } else if (i < 81920) {                // wn0t (k = 0..255)
        int j = i - 49152; int c = j >> 8, k = j & 255;
        wn0t[j] = f2bf(wn0[k * 128 + c]);
    } else if (i < 98304) {                // wn1t
        int j = i - 81920; int c = j >> 7, k = j & 127;
        wn1t[j] = f2bf(wn1[k * 128 + c]);
    } else if (i < 98304 + NN) {           // cnt = 0
        cnt[i - 98304] = 0;
    }
}

// K2 v5: MFMA [P|Q] = x @ Wcomb. 32 rows/block, 4 waves = (2 row-tiles x 2 col-halves).
// p8 layout (fp8 e4m3 quads): p8[n][4i+0,1] = P[2i],P[2i+1] ; p8[n][4i+2,3] = x[2i],x[2i+1]
// qb[n][128] = Q (bf16) ; xb[n][128] = x (bf16, for k_node + k_agg own-x)
__global__ __launch_bounds__(256) void k_pq_mfma(const float* __restrict__ x,
                                                 const u16* __restrict__ wcombt,
                                                 u8* __restrict__ p8, u16* __restrict__ qb,
                                                 u16* __restrict__ xb) {
    __shared__ u8  pq[32 * 272];   // fp8 quad tile, pad to 16B multiple
    __shared__ u16 qt[32 * 136];   // Q tile (bf16), row stride 272 B
    int r0 = blockIdx.x * 32;
    int tid = threadIdx.x, wid = tid >> 6, lane = tid & 63;
    int arow = lane & 15, kblk = lane >> 4;
    int rw = (wid & 1) * 16;            // row-tile offset (local)
    int ch = (wid >> 1) * 128;          // output-channel half
    // x -> fp8 x-slots of pq tile (+ coalesced bf16 copy to xb)
    for (int s = tid; s < 32 * 64; s += 256) {      // 32 rows x 64 pairs
        int r = s >> 6, i = s & 63;
        int n = r0 + r;
        float2 v = (n < NN) ? *(const float2*)&x[(size_t)n * 128 + 2 * i] : make_float2(0.f, 0.f);
        *(u16*)&pq[r * 272 + 4 * i + 2] = (u16)pk_fp8(v.x, v.y);
        if (n < NN) {
            ushort2 o = { f2bf(v.x), f2bf(v.y) };
            *(ushort2*)&xb[(size_t)n * 128 + 2 * i] = o;
        }
    }
    floatx4 acc[8];
#pragma unroll
    for (int n0 = 0; n0 < 8; n0++) acc[n0] = (floatx4)(0.f);
    int nrow = r0 + rw + arow; if (nrow >= NN) nrow = NN - 1;
#pragma unroll
    for (int ks = 0; ks < 4; ks++) {
        short8 a = cvt8(&x[(size_t)nrow * 128 + ks * 32 + kblk * 8]);
#pragma unroll
        for (int n0 = 0; n0 < 8; n0++) {
            short8 b = *(const short8*)&wcombt[(size_t)(ch + n0 * 16 + arow) * 128 + ks * 32 + kblk * 8];
            acc[n0] = MFMA(a, b, acc[n0], 0, 0, 0);
        }
    }
    // epilogue into LDS (wave-uniform col-half; LDS scatter is cheap)
#pragma unroll
    for (int n0 = 0; n0 < 8; n0++) {
#pragma unroll
        for (int j = 0; j < 4; j++) {
            int r = rw + kblk * 4 + j;
            int col = ch + n0 * 16 + arow;
            if (ch == 0) {
                u32 pk = pk_fp8(acc[n0][j], acc[n0][j]);
                pq[r * 272 + 4 * (col >> 1) + (col & 1)] = (u8)pk;
            } else {
                qt[r * 136 + (col - 128)] = f2bf(acc[n0][j]);
            }
        }
    }
    __syncthreads();
    // coalesced flush: p8 (16 x 16B chunks/row), qb (16 short8/row)
    for (int s = tid; s < 32 * 16; s += 256) {
        int r = s >> 4, cb = (s & 15) * 16;   // byte offset
        int n = r0 + r;
        if (n < NN) *(short8*)&p8[(size_t)n * 256 + cb] = *(const short8*)&pq[r * 272 + cb];
    }
    for (int s = tid; s < 32 * 16; s += 256) {
        int r = s >> 4, cb = (s & 15) * 8;
        int n = r0 + r;
        if (n < NN) *(short8*)&qb[(size_t)n * 128 + cb] = *(const short8*)&qt[r * 136 + cb];
    }
}

// K3: in-degree histogram, 4 edges/thread
__global__ void k_hist(const int* __restrict__ ei, int* __restrict__ cnt) {
    int e = (blockIdx.x * 256 + threadIdx.x) * 4;
    if (e + 4 <= NE) {
        int4 d = *(const int4*)&ei[NE + e];
        atomicAdd(&cnt[d.x], 1); atomicAdd(&cnt[d.y], 1);
        atomicAdd(&cnt[d.z], 1); atomicAdd(&cnt[d.w], 1);
    } else {
        for (int t = e; t < NE; t++) atomicAdd(&cnt[ei[NE + t]], 1);
    }
}

// K4a: per-block (512) inclusive scan
__global__ void k_scan1(const int* __restrict__ cnt, int* __restrict__ incl, int* __restrict__ bsum) {
    __shared__ int s[512];
    int i = blockIdx.x * 512 + threadIdx.x;
    int v = (i < NN) ? cnt[i] : 0;
    s[threadIdx.x] = v; __syncthreads();
    for (int off = 1; off < 512; off <<= 1) {
        int t = (threadIdx.x >= (unsigned)off) ? s[threadIdx.x - off] : 0;
        __syncthreads();
        s[threadIdx.x] += t; __syncthreads();
    }
    if (i < NN) incl[i] = s[threadIdx.x];
    if (threadIdx.x == 511) bsum[blockIdx.x] = s[511];
}

// K4b: exclusive scan of block sums (nb <= 128)
__global__ void k_scan2(int* __restrict__ bsum, int nb) {
    __shared__ int s[128];
    int t = threadIdx.x;
    s[t] = (t < nb) ? bsum[t] : 0;
    __syncthreads();
    if (t == 0) { int run = 0; for (int b = 0; b < nb; b++) { int v = s[b]; s[b] = run; run += v; } }
    __syncthreads();
    if (t < nb) bsum[t] = s[t];
}

// K4c
__global__ void k_scan3(const int* __restrict__ incl, const int* __restrict__ bsum,
                        const int* __restrict__ cnt, int* __restrict__ offs, int* __restrict__ cursor) {
    int i = blockIdx.x * 512 + threadIdx.x;
    if (i < NN) {
        int e = incl[i] + bsum[i >> 9];
        offs[i + 1] = e;
        cursor[i] = e - cnt[i];
        if (i == 0) offs[0] = 0;
    }
}

// K5: scatter edge srcs into CSR slots grouped by dst (4 edges/thread, int4)
__global__ void k_slots(const int* __restrict__ ei, int* __restrict__ cursor, int* __restrict__ srcs) {
    int e = (blockIdx.x * 256 + threadIdx.x) * 4;
    if (e + 4 <= NE) {
        int4 sv = *(const int4*)&ei[e];
        int4 dv = *(const int4*)&ei[NE + e];
        int p0 = atomicAdd(&cursor[dv.x], 1); srcs[p0] = sv.x;
        int p1 = atomicAdd(&cursor[dv.y], 1); srcs[p1] = sv.y;
        int p2_ = atomicAdd(&cursor[dv.z], 1); srcs[p2_] = sv.z;
        int p3 = atomicAdd(&cursor[dv.w], 1); srcs[p3] = sv.w;
    } else {
        for (int t = e; t < NE; t++) {
            int p = atomicAdd(&cursor[ei[NE + t]], 1);
            srcs[p] = ei[t];
        }
    }
}

// K6 v4: one wave per node; fp8 gathers (4 B/lane = 256 B/edge).
// Unmasked full 8-batches + one masked tail batch; index prefetch pipeline.
//   esumx[n][0:128]   = esum/max(cnt,1)
//   esumx[n][128:256] = (xsum - cnt*x[n])/max(cnt,1)
__global__ __launch_bounds__(256) void k_agg(const u8* __restrict__ p8, const u16* __restrict__ qb,
                                             const u16* __restrict__ xb,
                                             const int* __restrict__ offs, const int* __restrict__ srcs,
                                             u16* __restrict__ esumx) {
    const u32* p8r = (const u32*)p8;     // row = 64 dwords
    int wave = threadIdx.x >> 6, lane = threadIdx.x & 63;
    int n = blockIdx.x * 4 + wave;
    if (n >= NN) return;
    int beg = offs[n], end = offs[n + 1];
    ushort2 qv = *(const ushort2*)(qb + (size_t)n * 128 + 2 * lane);
    float q0 = bf2f(qv.x), q1 = bf2f(qv.y);
    float e0 = 0.f, e1 = 0.f, s0 = 0.f, s1 = 0.f;
    int s = beg;
    if (end > beg) {
        int last = end - 1;
        int sr[8];
#pragma unroll
        for (int j = 0; j < 8; j++) { int t = beg + j; sr[j] = srcs[t <= last ? t : last]; }
        // full batches: no masking
        for (; s + 8 <= end; s += 8) {
            u32 d[8];
#pragma unroll
            for (int j = 0; j < 8; j++) d[j] = p8r[(size_t)sr[j] * 64 + lane];
            int nb = s + 8;
            if (nb < end) {                 // prefetch next batch's indices during compute
#pragma unroll
                for (int j = 0; j < 8; j++) { int t = nb + j; sr[j] = srcs[t <= last ? t : last]; }
            }
#pragma unroll
            for (int j = 0; j < 8; j++) {
                f32x2 pp = __builtin_amdgcn_cvt_pk_f32_fp8(d[j], false);
                f32x2 xp = __builtin_amdgcn_cvt_pk_f32_fp8(d[j], true);
                e0 += elu_fast(pp[0] + q0);
                e1 += elu_fast(pp[1] + q1);
                s0 += xp[0]; s1 += xp[1];
            }
        }
        // masked tail batch (indices already clamped in sr)
        if (s < end) {
            u32 d[8];
#pragma unroll
            for (int j = 0; j < 8; j++) d[j] = p8r[(size_t)sr[j] * 64 + lane];
#pragma unroll
            for (int j = 0; j < 8; j++) {
                bool live = (s + j < end);  // wave-uniform
                f32x2 pp = __builtin_amdgcn_cvt_pk_f32_fp8(d[j], false);
                f32x2 xp = __builtin_amdgcn_cvt_pk_f32_fp8(d[j], true);
                float c0 = elu_fast(pp[0] + q0), c1 = elu_fast(pp[1] + q1);
                e0 += live ? c0 : 0.f;
                e1 += live ? c1 : 0.f;
                s0 += live ? xp[0] : 0.f;
                s1 += live ? xp[1] : 0.f;
            }
        }
    }
    float cntf = (float)(end - beg);
    float inv = 1.f / fmaxf(cntf, 1.f);
    ushort2 xo = *(const ushort2*)(xb + (size_t)n * 128 + 2 * lane);  // own x (bf16)
    s0 = (s0 - cntf * bf2f(xo.x)) * inv;
    s1 = (s1 - cntf * bf2f(xo.y)) * inv;
    e0 *= inv; e1 *= inv;
    ushort2 oe = { f2bf(e0), f2bf(e1) };
    ushort2 os = { f2bf(s0), f2bf(s1) };
    *(ushort2*)(esumx + (size_t)n * 256 + 2 * lane) = oe;
    *(ushort2*)(esumx + (size_t)n * 256 + 128 + 2 * lane) = os;
}

// K7 v3: MFMA node MLP. 128 rows/block, 4 waves; wave wid owns rows wid*32..wid*32+31
// end-to-end (stage + compute + flush), so NO barriers. All global inputs prefetched
// at entry into registers (one latency round-trip instead of a serial chain).
__global__ __launch_bounds__(256, 2) void k_node_mfma(const float* __restrict__ x,
                                                      const u16* __restrict__ xb,
                                                      const u16* __restrict__ esumx,
                                                      const u16* __restrict__ we1t,
                                                      const u16* __restrict__ wn0t,
                                                      const u16* __restrict__ wn1t,
                                                      float* __restrict__ out) {
    __shared__ u16 tile[128 * 136];   // pad 8 u16
    int r0 = blockIdx.x * 128;
    int tid = threadIdx.x, wid = tid >> 6, lane = tid & 63;
    int arow = lane & 15, kblk = lane >> 4;
    int rbase = wid * 32;

    // ---- prefetch ALL global inputs for this wave ----
    int nrow[2];
#pragma unroll
    for (int rt = 0; rt < 2; rt++) {
        int n = r0 + rbase + rt * 16 + arow; if (n >= NN) n = NN - 1;
        nrow[rt] = n;
    }
    short8 stg[8];                                    // xsum' staging: 32 rows x 16 chunks /64 lanes
#pragma unroll
    for (int t = 0; t < 8; t++) {
        int idx = t * 64 + lane;
        int r = idx >> 4, cb = (idx & 15) * 8;
        int n = r0 + rbase + r; if (n >= NN) n = NN - 1;
        stg[t] = *(const short8*)&esumx[(size_t)n * 256 + 128 + cb];
    }
    short8 a1[2][4], ax[2][4];                        // stage-1 esum frags + stage-2 x frags
#pragma unroll
    for (int rt = 0; rt < 2; rt++)
#pragma unroll
        for (int ks = 0; ks < 4; ks++) {
            a1[rt][ks] = *(const short8*)&esumx[(size_t)nrow[rt] * 256 + ks * 32 + kblk * 8];
            ax[rt][ks] = *(const short8*)&xb[(size_t)nrow[rt] * 128 + ks * 32 + kblk * 8];
        }
    // xsum' -> LDS (own rows only)
#pragma unroll
    for (int t = 0; t < 8; t++) {
        int idx = t * 64 + lane;
        int r = rbase + (idx >> 4), cb = (idx & 15) * 8;
        *(short8*)&tile[r * 136 + cb] = stg[t];
    }
    // ---- stage 1: T = esum' @ We1 ----
    floatx4 acc[2][8];
#pragma unroll
    for (int rt = 0; rt < 2; rt++)
#pragma unroll
        for (int n0 = 0; n0 < 8; n0++) acc[rt][n0] = (floatx4)(0.f);
#pragma unroll
    for (int ks = 0; ks < 4; ks++)
#pragma unroll
        for (int n0 = 0; n0 < 8; n0++) {
            short8 b = *(const short8*)&we1t[(size_t)(n0 * 16 + arow) * 128 + ks * 32 + kblk * 8];
            acc[0][n0] = MFMA(a1[0][ks], b, acc[0][n0], 0, 0, 0);
            acc[1][n0] = MFMA(a1[1][ks], b, acc[1][n0], 0, 0, 0);
        }
    // ---- m = T + xsum' (own rows, in place; within-wave LDS RAW ordering) ----
#pragma unroll
    for (int rt = 0; rt < 2; rt++)
#pragma unroll
        for (int n0 = 0; n0 < 8; n0++)
#pragma unroll
            for (int j = 0; j < 4; j++) {
                int rloc = rbase + rt * 16 + kblk * 4 + j;
                int col = n0 * 16 + arow;
                float m = acc[rt][n0][j] + bf2f(tile[rloc * 136 + col]);
                tile[rloc * 136 + col] = f2bf(m);
            }
    // ---- stage 2: h = ELU(x@Wn0a + m@Wn0b) ----
#pragma unroll
    for (int rt = 0; rt < 2; rt++)
#pragma unroll
        for (int n0 = 0; n0 < 8; n0++) acc[rt][n0] = (floatx4)(0.f);
#pragma unroll
    for (int ks = 0; ks < 4; ks++) {
        short8 am[2];
#pragma unroll
        for (int rt = 0; rt < 2; rt++)
            am[rt] = *(const short8*)&tile[(rbase + rt * 16 + arow) * 136 + ks * 32 + kblk * 8];
#pragma unroll
        for (int n0 = 0; n0 < 8; n0++) {
            short8 bx = *(const short8*)&wn0t[(size_t)(n0 * 16 + arow) * 256 + ks * 32 + kblk * 8];
            short8 bm = *(const short8*)&wn0t[(size_t)(n0 * 16 + arow) * 256 + 128 + ks * 32 + kblk * 8];
#pragma unroll
            for (int rt = 0; rt < 2; rt++) {
                acc[rt][n0] = MFMA(ax[rt][ks], bx, acc[rt][n0], 0, 0, 0);
                acc[rt][n0] = MFMA(am[rt], bm, acc[rt][n0], 0, 0, 0);
            }
        }
    }
    // ---- h -> tile (own rows) ----
#pragma unroll
    for (int rt = 0; rt < 2; rt++)
#pragma unroll
        for (int n0 = 0; n0 < 8; n0++)
#pragma unroll
            for (int j = 0; j < 4; j++) {
                int rloc = rbase + rt * 16 + kblk * 4 + j;
                tile[rloc * 136 + n0 * 16 + arow] = f2bf(elu_fast(acc[rt][n0][j]));
            }
    // ---- stage 3: r = h @ Wn1 ----
#pragma unroll
    for (int rt = 0; rt < 2; rt++)
#pragma unroll
        for (int n0 = 0; n0 < 8; n0++) acc[rt][n0] = (floatx4)(0.f);
#pragma unroll
    for (int ks = 0; ks < 4; ks++) {
        short8 a[2];
#pragma unroll
        for (int rt = 0; rt < 2; rt++)
            a[rt] = *(const short8*)&tile[(rbase + rt * 16 + arow) * 136 + ks * 32 + kblk * 8];
#pragma unroll
        for (int n0 = 0; n0 < 8; n0++) {
            short8 b = *(const short8*)&wn1t[(size_t)(n0 * 16 + arow) * 128 + ks * 32 + kblk * 8];
            acc[0][n0] = MFMA(a[0], b, acc[0][n0], 0, 0, 0);
            acc[1][n0] = MFMA(a[1], b, acc[1][n0], 0, 0, 0);
        }
    }
    // ---- r -> tile (bf16), per-wave coalesced float4 epilogue ----
#pragma unroll
    for (int rt = 0; rt < 2; rt++)
#pragma unroll
        for (int n0 = 0; n0 < 8; n0++)
#pragma unroll
            for (int j = 0; j < 4; j++)
                tile[(rbase + rt * 16 + kblk * 4 + j) * 136 + n0 * 16 + arow] = f2bf(acc[rt][n0][j]);
#pragma unroll
    for (int t = 0; t < 16; t++) {
        int idx = t * 64 + lane;                 // 32 rows x 32 float4-chunks
        int r = idx >> 5, cb = (idx & 31) * 4;
        int n = r0 + rbase + r;
        if (n < NN) {
            float4 xv = *(const float4*)&x[(size_t)n * 128 + cb];
            ushort4 tv = *(const ushort4*)&tile[(rbase + r) * 136 + cb];
            float4 o = { xv.x + bf2f(tv.x), xv.y + bf2f(tv.y), xv.z + bf2f(tv.z), xv.w + bf2f(tv.w) };
            *(float4*)&out[(size_t)n * 128 + cb] = o;
        }
    }
}

extern "C" void kernel_launch(void* const* d_in, const int* in_sizes, int n_in,
                              void* d_out, int out_size, void* d_ws, size_t ws_size,
                              hipStream_t stream) {
    const float* x       = (const float*)d_in[0];
    const int* ei        = (const int*)d_in[1];   // int64 in reference -> int32 from harness
    const float* we0     = (const float*)d_in[2];
    const float* we1     = (const float*)d_in[3];
    const float* wn0     = (const float*)d_in[4];
    const float* wn1     = (const float*)d_in[5];
    float* out           = (float*)d_out;

    char* w = (char*)d_ws;
    size_t off = 0;
    auto alloc = [&](size_t bytes) -> void* {
        off = (off + 255) & ~(size_t)255;
        void* p = w + off;
        off += bytes;
        return p;
    };
    u16*   wcombt = (u16*)alloc(256 * 128 * sizeof(u16));
    u16*   we1t   = (u16*)alloc(128 * 128 * sizeof(u16));
    u16*   wn0t   = (u16*)alloc(128 * 256 * sizeof(u16));
    u16*   wn1t   = (u16*)alloc(128 * 128 * sizeof(u16));
    u8*    p8     = (u8*)alloc((size_t)NN * 256 * sizeof(u8));
    u16*   qb     = (u16*)alloc((size_t)NN * 128 * sizeof(u16));
    u16*   xb     = (u16*)alloc((size_t)NN * 128 * sizeof(u16));
    u16*   esumx  = (u16*)alloc((size_t)NN * 256 * sizeof(u16));
    int*   cnt    = (int*)alloc((size_t)NN * sizeof(int));
    int*   incl   = (int*)alloc((size_t)NN * sizeof(int));
    int*   offs   = (int*)alloc((size_t)(NN + 1) * sizeof(int));
    int*   cursor = (int*)alloc((size_t)NN * sizeof(int));
    int*   bsum   = (int*)alloc(128 * sizeof(int));
    int*   srcs   = (int*)alloc((size_t)NE * sizeof(int));
    (void)ws_size; (void)in_sizes; (void)n_in; (void)out_size;  // ~68 MB of d_ws used

    k_wb<<<(98304 + NN + 255) / 256, 256, 0, stream>>>(we0, we1, wn0, wn1,
                                                       wcombt, we1t, wn0t, wn1t, cnt);
    k_pq_mfma<<<(NN + 31) / 32, 256, 0, stream>>>(x, wcombt, p8, qb, xb);
    k_hist<<<(NE / 4 + 255) / 256, 256, 0, stream>>>(ei, cnt);
    int nb = (NN + 511) / 512;
    k_scan1<<<nb, 512, 0, stream>>>(cnt, incl, bsum);
    k_scan2<<<1, 128, 0, stream>>>(bsum, nb);
    k_scan3<<<nb, 512, 0, stream>>>(incl, bsum, cnt, offs, cursor);
    k_slots<<<(NE / 4 + 255) / 256, 256, 0, stream>>>(ei, cursor, srcs);
    k_agg<<<(NN + 3) / 4, 256, 0, stream>>>(p8, qb, xb, offs, srcs, esumx);
    k_node_mfma<<<(NN + 127) / 128, 256, 0, stream>>>(x, xb, esumx, we1t, wn0t, wn1t, out);
}